// Round 21
// baseline (179.207 us; speedup 1.0000x reference)
//
#include <hip/hip_runtime.h>
#include <math.h>

#define B_   2
#define S_   3072
#define C_   256
#define NH   8
#define HD   32
#define HALF 16
#define NELEM (B_*S_*C_)   // 1,572,864
#define MLROWS (B_*NH*S_)  // 49,152 rows per split
#define TABN  (S_*HALF)    // 49,152 rope table entries

typedef __attribute__((ext_vector_type(8))) __bf16 bf16x8;
typedef __attribute__((ext_vector_type(4))) float  f32x4;

__device__ __forceinline__ float dot4(float4 a, float4 b) {
    return a.x*b.x + a.y*b.y + a.z*b.z + a.w*b.w;
}

// single-instruction 2^x (v_exp_f32). Scores are pre-scaled by log2(e) in the
// q projection, so softmax runs in base-2: p = 2^(s' - m'). Avoids the v_mul
// that __expf emits before every v_exp_f32.
__device__ __forceinline__ float fexp2(float x) {
    float r;
    asm("v_exp_f32 %0, %1" : "=v"(r) : "v"(x));
    return r;
}

// direct global->LDS copy, 16B per lane; LDS dest is wave-uniform base + lane*16
__device__ __forceinline__ void gload_lds16(const void* g, void* l) {
    __builtin_amdgcn_global_load_lds(
        (const __attribute__((address_space(1))) unsigned int*)g,
        (__attribute__((address_space(3))) unsigned int*)l, 16, 0, 0);
}

// fp32 -> (hi, lo) bf16 split: hi = bf16(x), lo = bf16(x - hi). hi*hi+hi*lo+lo*hi
// reconstructs products to ~2^-17 relative.
__device__ __forceinline__ void bsplit(float x, unsigned short& h, unsigned short& lo) {
    __bf16 hb = (__bf16)x;
    float hf = (float)hb;
    __bf16 lb = (__bf16)(x - hf);
    h  = __builtin_bit_cast(unsigned short, hb);
    lo = __builtin_bit_cast(unsigned short, lb);
}

// ---------------- fused prep: x split | W splits | rope table ----------------------
// grid 1984 blocks: [0,1536) fsplit(x), [1536,1792) wsplit, [1792,1984) rope table
__global__ __launch_bounds__(256) void prep_kernel(
        const float* __restrict__ x,
        const float* __restrict__ Wq, const float* __restrict__ Wk,
        const float* __restrict__ Wv, const float* __restrict__ Wo,
        unsigned short* __restrict__ xhi, unsigned short* __restrict__ xlo,
        unsigned short* __restrict__ wqh, unsigned short* __restrict__ wql,
        unsigned short* __restrict__ wkh, unsigned short* __restrict__ wkl,
        unsigned short* __restrict__ wvh, unsigned short* __restrict__ wvl,
        unsigned short* __restrict__ woh, unsigned short* __restrict__ wol,
        float2* __restrict__ tbl)
{
    const int bx = blockIdx.x;
    const int tid = threadIdx.x;
    if (bx < 1536) {                       // x split: NELEM/4 float4s
        const size_t i = (size_t)bx * 256 + tid;
        float4 xv = *(const float4*)&x[i*4];
        ushort4 h, l; unsigned short hh, ll;
        bsplit(xv.x, hh, ll); h.x = hh; l.x = ll;
        bsplit(xv.y, hh, ll); h.y = hh; l.y = ll;
        bsplit(xv.z, hh, ll); h.z = hh; l.z = ll;
        bsplit(xv.w, hh, ll); h.w = hh; l.w = ll;
        *(ushort4*)&xhi[i*4] = h;
        *(ushort4*)&xlo[i*4] = l;
    } else if (bx < 1792) {                // weight splits: 4 mats x 64 blocks
        const int wb  = bx - 1536;
        const int mat = wb >> 6;
        const float* src; unsigned short *h, *l;
        if      (mat == 0) { src = Wq; h = wqh; l = wql; }
        else if (mat == 1) { src = Wk; h = wkh; l = wkl; }
        else if (mat == 2) { src = Wv; h = wvh; l = wvl; }
        else               { src = Wo; h = woh; l = wol; }
        const size_t i = (size_t)(wb & 63) * 256 + tid;
        float4 xv = *(const float4*)&src[i*4];
        ushort4 hv, lv; unsigned short hh, ll;
        bsplit(xv.x, hh, ll); hv.x = hh; lv.x = ll;
        bsplit(xv.y, hh, ll); hv.y = hh; lv.y = ll;
        bsplit(xv.z, hh, ll); hv.z = hh; lv.z = ll;
        bsplit(xv.w, hh, ll); hv.w = hh; lv.w = ll;
        *(ushort4*)&h[i*4] = hv;
        *(ushort4*)&l[i*4] = lv;
    } else {                               // rope table: 192 blocks
        const int idx = (bx - 1792) * 256 + tid;   // 0..49151
        const int j = idx & 15;
        const int s = idx >> 4;
        const double invf = exp(-log(10000.0) * (double)j * (1.0 / 16.0));
        const float  angf = (float)((double)s * invf);
        double sn, cs;
        sincos((double)angf, &sn, &cs);
        tbl[idx] = make_float2((float)cs, (float)sn);
    }
}

// ---------------- MFMA GEMM: out[M x 256] = (A @ W^T (+bias)) * scl ---------------
// 1 wave per 32x32 output tile; operands as bf16 hi/lo [row][256]; 3-term split.
// Frags loaded DIRECTLY from global (L2-resident; 64B segments per 4-lane group).
// D-layout (R14/R15-verified): row(n) = 16nh + 4gq + reg, col(m) = 16mh + cq.
__device__ __forceinline__ void gemm_mfma_body(
        const unsigned short* __restrict__ Ahi, const unsigned short* __restrict__ Alo,
        const unsigned short* __restrict__ Whi, const unsigned short* __restrict__ Wlo,
        const float* __restrict__ bias, float* __restrict__ out, float scl)
{
    const int tid = threadIdx.x;
    const int cq  = tid & 15;
    const int gq  = tid >> 4;
    const int m0  = blockIdx.x * 32;
    const int n0  = blockIdx.y * 32;

    const size_t a0 = (size_t)(m0 + cq)      * C_ + gq*8;   // B-op rows (m)
    const size_t a1 = (size_t)(m0 + 16 + cq) * C_ + gq*8;
    const size_t w0 = (size_t)(n0 + cq)      * C_ + gq*8;   // A-op rows (n)
    const size_t w1 = (size_t)(n0 + 16 + cq) * C_ + gq*8;

    f32x4 acc00 = {0,0,0,0}, acc01 = {0,0,0,0};   // [nh][mh]
    f32x4 acc10 = {0,0,0,0}, acc11 = {0,0,0,0};

    #pragma unroll
    for (int kk = 0; kk < 8; ++kk) {
        const int ko = kk * 32;
        const bf16x8 wh0 = *(const bf16x8*)(Whi + w0 + ko);
        const bf16x8 wh1 = *(const bf16x8*)(Whi + w1 + ko);
        const bf16x8 wl0 = *(const bf16x8*)(Wlo + w0 + ko);
        const bf16x8 wl1 = *(const bf16x8*)(Wlo + w1 + ko);
        const bf16x8 ah0 = *(const bf16x8*)(Ahi + a0 + ko);
        const bf16x8 ah1 = *(const bf16x8*)(Ahi + a1 + ko);
        const bf16x8 al0 = *(const bf16x8*)(Alo + a0 + ko);
        const bf16x8 al1 = *(const bf16x8*)(Alo + a1 + ko);
        acc00 = __builtin_amdgcn_mfma_f32_16x16x32_bf16(wh0, ah0, acc00, 0, 0, 0);
        acc01 = __builtin_amdgcn_mfma_f32_16x16x32_bf16(wh0, ah1, acc01, 0, 0, 0);
        acc10 = __builtin_amdgcn_mfma_f32_16x16x32_bf16(wh1, ah0, acc10, 0, 0, 0);
        acc11 = __builtin_amdgcn_mfma_f32_16x16x32_bf16(wh1, ah1, acc11, 0, 0, 0);
        acc00 = __builtin_amdgcn_mfma_f32_16x16x32_bf16(wh0, al0, acc00, 0, 0, 0);
        acc01 = __builtin_amdgcn_mfma_f32_16x16x32_bf16(wh0, al1, acc01, 0, 0, 0);
        acc10 = __builtin_amdgcn_mfma_f32_16x16x32_bf16(wh1, al0, acc10, 0, 0, 0);
        acc11 = __builtin_amdgcn_mfma_f32_16x16x32_bf16(wh1, al1, acc11, 0, 0, 0);
        acc00 = __builtin_amdgcn_mfma_f32_16x16x32_bf16(wl0, ah0, acc00, 0, 0, 0);
        acc01 = __builtin_amdgcn_mfma_f32_16x16x32_bf16(wl0, ah1, acc01, 0, 0, 0);
        acc10 = __builtin_amdgcn_mfma_f32_16x16x32_bf16(wl1, ah0, acc10, 0, 0, 0);
        acc11 = __builtin_amdgcn_mfma_f32_16x16x32_bf16(wl1, ah1, acc11, 0, 0, 0);
    }

    float4 bv0 = make_float4(0.f, 0.f, 0.f, 0.f);
    float4 bv1 = make_float4(0.f, 0.f, 0.f, 0.f);
    if (bias) {
        bv0 = *(const float4*)&bias[n0 + 4*gq];
        bv1 = *(const float4*)&bias[n0 + 16 + 4*gq];
    }
    float4 o;
    o = make_float4((acc00[0]+bv0.x)*scl, (acc00[1]+bv0.y)*scl,
                    (acc00[2]+bv0.z)*scl, (acc00[3]+bv0.w)*scl);
    *(float4*)&out[(size_t)(m0 + cq)*C_ + n0 + 4*gq] = o;
    o = make_float4((acc01[0]+bv0.x)*scl, (acc01[1]+bv0.y)*scl,
                    (acc01[2]+bv0.z)*scl, (acc01[3]+bv0.w)*scl);
    *(float4*)&out[(size_t)(m0 + 16 + cq)*C_ + n0 + 4*gq] = o;
    o = make_float4((acc10[0]+bv1.x)*scl, (acc10[1]+bv1.y)*scl,
                    (acc10[2]+bv1.z)*scl, (acc10[3]+bv1.w)*scl);
    *(float4*)&out[(size_t)(m0 + cq)*C_ + n0 + 16 + 4*gq] = o;
    o = make_float4((acc11[0]+bv1.x)*scl, (acc11[1]+bv1.y)*scl,
                    (acc11[2]+bv1.z)*scl, (acc11[3]+bv1.w)*scl);
    *(float4*)&out[(size_t)(m0 + 16 + cq)*C_ + n0 + 16 + 4*gq] = o;
}

__global__ __launch_bounds__(64) void qkv_mfma_kernel(
        const unsigned short* __restrict__ xhi, const unsigned short* __restrict__ xlo,
        const unsigned short* __restrict__ wqh, const unsigned short* __restrict__ wql,
        const unsigned short* __restrict__ wkh, const unsigned short* __restrict__ wkl,
        const unsigned short* __restrict__ wvh, const unsigned short* __restrict__ wvl,
        const float* __restrict__ qb, const float* __restrict__ vb,
        float* __restrict__ q, float* __restrict__ k, float* __restrict__ v)
{
    // q scale = (1/sqrt(32)) * log2(e): softmax runs in base-2 downstream
    if (blockIdx.z == 0)
        gemm_mfma_body(xhi, xlo, wqh, wql, qb, q,
                       0.17677669529663687f * 1.4426950408889634f);
    else if (blockIdx.z == 1)
        gemm_mfma_body(xhi, xlo, wkh, wkl, nullptr, k, 1.0f);
    else
        gemm_mfma_body(xhi, xlo, wvh, wvl, vb, v, 1.0f);
}

__global__ __launch_bounds__(64) void out_gemm_mfma_kernel(
        const unsigned short* __restrict__ chi, const unsigned short* __restrict__ clo,
        const unsigned short* __restrict__ woh, const unsigned short* __restrict__ wol,
        const float* __restrict__ bo, float* __restrict__ out)
{
    gemm_mfma_body(chi, clo, woh, wol, bo, out, 1.0f);
}

// ---------------- fp32 GEMM (fallback path only; R16-validated) -------------------
__device__ __forceinline__ void gemm_nt_body(const float* __restrict__ A,
                                             const float* __restrict__ W,
                                             const float* __restrict__ bias,
                                             float* __restrict__ out,
                                             float scl)
{
    __shared__ float As[2][64*32];
    __shared__ float Ws[2][64*32];

    const int tid  = threadIdx.x;
    const int wv   = tid >> 6;
    const int tx4  = (tid & 15) * 4;
    const int ty4  = (tid >> 4) * 4;
    const int row0 = blockIdx.x * 64;
    const int col0 = blockIdx.y * 64;

    const int d0  = tid, d1 = tid + 256;
    const int r0s = d0 >> 3, r1s = d1 >> 3;
    const int c0s = (d0 & 7) ^ ((r0s >> 2) & 7);
    const int c1s = (d1 & 7) ^ ((r1s >> 2) & 7);
    const float* a0p = A + (size_t)(row0 + r0s)*C_ + c0s*4;
    const float* a1p = A + (size_t)(row0 + r1s)*C_ + c1s*4;
    const float* w0p = W + (size_t)(col0 + r0s)*C_ + c0s*4;
    const float* w1p = W + (size_t)(col0 + r1s)*C_ + c1s*4;
    const int dst = wv * 256;

#define GSTAGE(kc, buf) { \
        gload_lds16(a0p + (kc), &As[buf][dst]);        \
        gload_lds16(a1p + (kc), &As[buf][dst + 1024]); \
        gload_lds16(w0p + (kc), &Ws[buf][dst]);        \
        gload_lds16(w1p + (kc), &Ws[buf][dst + 1024]); }

    float acc[4][4] = {};
    const int xa = ((tid >> 4) & 7) * 4;
    const int xw = (tid & 7) * 4;

    GSTAGE(0, 0);
    __syncthreads();

    for (int kk = 0; kk < 8; ++kk) {
        const int buf = kk & 1;
        if (kk + 1 < 8) GSTAGE((kk + 1) * 32, buf ^ 1);

        const float* Ab = &As[buf][ty4 * 32];
        const float* Wb = &Ws[buf][tx4 * 32];
        #pragma unroll
        for (int p = 0; p < 8; ++p) {
            const int oa = (p * 4) ^ xa;
            const int ow = (p * 4) ^ xw;
            float4 a0 = *(const float4*)&Ab[oa];
            float4 a1 = *(const float4*)&Ab[32 + oa];
            float4 a2 = *(const float4*)&Ab[64 + oa];
            float4 a3 = *(const float4*)&Ab[96 + oa];
            float4 w0 = *(const float4*)&Wb[ow];
            float4 w1 = *(const float4*)&Wb[32 + ow];
            float4 w2 = *(const float4*)&Wb[64 + ow];
            float4 w3 = *(const float4*)&Wb[96 + ow];
            acc[0][0] += dot4(a0,w0); acc[0][1] += dot4(a0,w1);
            acc[0][2] += dot4(a0,w2); acc[0][3] += dot4(a0,w3);
            acc[1][0] += dot4(a1,w0); acc[1][1] += dot4(a1,w1);
            acc[1][2] += dot4(a1,w2); acc[1][3] += dot4(a1,w3);
            acc[2][0] += dot4(a2,w0); acc[2][1] += dot4(a2,w1);
            acc[2][2] += dot4(a2,w2); acc[2][3] += dot4(a2,w3);
            acc[3][0] += dot4(a3,w0); acc[3][1] += dot4(a3,w1);
            acc[3][2] += dot4(a3,w2); acc[3][3] += dot4(a3,w3);
        }
        __syncthreads();
    }
#undef GSTAGE

    float4 bv = make_float4(0.f, 0.f, 0.f, 0.f);
    if (bias) bv = *(const float4*)&bias[col0 + tx4];
    #pragma unroll
    for (int rr = 0; rr < 4; ++rr) {
        float4 o = make_float4((acc[rr][0] + bv.x)*scl, (acc[rr][1] + bv.y)*scl,
                               (acc[rr][2] + bv.z)*scl, (acc[rr][3] + bv.w)*scl);
        *(float4*)&out[(size_t)(row0 + ty4 + rr)*C_ + col0 + tx4] = o;
    }
}

__global__ __launch_bounds__(256) void qkv_kernel(
        const float* __restrict__ x,
        const float* __restrict__ Wq, const float* __restrict__ Wk, const float* __restrict__ Wv,
        const float* __restrict__ qb, const float* __restrict__ vb,
        float* __restrict__ q, float* __restrict__ k, float* __restrict__ v)
{
    if      (blockIdx.z == 0) gemm_nt_body(x, Wq, qb,      q, 0.17677669529663687f);
    else if (blockIdx.z == 1) gemm_nt_body(x, Wk, nullptr, k, 1.0f);
    else                      gemm_nt_body(x, Wv, vb,      v, 1.0f);
}

__global__ __launch_bounds__(256) void out_gemm_kernel(
        const float* __restrict__ ctx, const float* __restrict__ Wo,
        const float* __restrict__ bo, float* __restrict__ out)
{
    gemm_nt_body(ctx, Wo, bo, out, 1.0f);
}

// ---------------- RoPE (in place on q and k); TAB path also emits bf16 splits -----
template<bool TAB>
__global__ __launch_bounds__(256) void rope_kernel(float* __restrict__ q, float* __restrict__ k,
                                                   const float2* __restrict__ tbl,
                                                   unsigned short* __restrict__ qhi,
                                                   unsigned short* __restrict__ qlo,
                                                   unsigned short* __restrict__ khi,
                                                   unsigned short* __restrict__ klo)
{
    const int idx = blockIdx.x * 256 + threadIdx.x;
    const int per_tensor = B_ * S_ * NH * HALF;       // 786432
    const bool isq = (idx < per_tensor);
    float* t = isq ? q : k;
    const int i   = isq ? idx : idx - per_tensor;
    const int j   = i & 15;
    const int hh  = (i >> 4) & 7;
    const int row = i >> 7;
    const int s   = (row >= S_) ? (row - S_) : row;

    float c, sf;
    if (TAB) {
        const float2 cs2 = tbl[(s << 4) | j];
        c = cs2.x; sf = cs2.y;
    } else {
        const double invf = exp(-log(10000.0) * (double)j * (1.0 / 16.0));
        const float  angf = (float)((double)s * invf);
        double sn, cd;
        sincos((double)angf, &sn, &cd);
        c = (float)cd; sf = (float)sn;
    }

    const size_t base = (size_t)row * C_ + hh * HD + j;
    const float t1 = t[base];
    const float t2 = t[base + HALF];
    const float o1 = t1 * c - t2 * sf;
    const float o2 = t2 * c + t1 * sf;
    t[base]        = o1;
    t[base + HALF] = o2;

    if (TAB) {
        unsigned short* hi = isq ? qhi : khi;
        unsigned short* lo = isq ? qlo : klo;
        const size_t sb = ((size_t)row * NH + hh) * 32;
        unsigned short h1, l1, h2, l2;
        bsplit(o1, h1, l1);
        bsplit(o2, h2, l2);
        hi[sb + j]      = h1;  lo[sb + j]      = l1;
        hi[sb + j + 16] = h2;  lo[sb + j + 16] = l2;
    }
}

// ---------------- V transpose + bf16 split, pi-ordered -----------------------------
__global__ __launch_bounds__(256) void vsplit_kernel(const float* __restrict__ v,
                                                     unsigned short* __restrict__ vthi,
                                                     unsigned short* __restrict__ vtlo)
{
    __shared__ float T[64][33];
    const int t  = threadIdx.x;
    const int kb = blockIdx.x;       // 64-kv chunk (0..47)
    const int hh = blockIdx.y;
    const int b  = blockIdx.z;
    const size_t rowbase = (size_t)b*S_ + kb*64;

    {   // load 64 rows x 32 d, coalesced
        const int r = t >> 2;        // 0..63
        const int p = t & 3;         // float4 piece
        float4 a  = *(const float4*)&v[(rowbase + r)*C_ + hh*32 + p*4];
        float4 b2 = *(const float4*)&v[(rowbase + r)*C_ + hh*32 + 16 + p*4];
        *(float4*)&T[r][p*4]      = a;
        *(float4*)&T[r][16 + p*4] = b2;
    }
    __syncthreads();

    const int d = t >> 3;
    const int j = t & 7;
    const int pa = (j & 1)*16 + ((j & 2) ? 4 : 0);   // pi position of first 4-run
    const int pb = pa + 8;                           // second 4-run
    ushort4 ha, la, hb, lb;
    unsigned short hs, ls;
    {
        float x0 = T[8*j+0][d], x1 = T[8*j+1][d], x2 = T[8*j+2][d], x3 = T[8*j+3][d];
        bsplit(x0, hs, ls); ha.x = hs; la.x = ls;
        bsplit(x1, hs, ls); ha.y = hs; la.y = ls;
        bsplit(x2, hs, ls); ha.z = hs; la.z = ls;
        bsplit(x3, hs, ls); ha.w = hs; la.w = ls;
        float y0 = T[8*j+4][d], y1 = T[8*j+5][d], y2 = T[8*j+6][d], y3 = T[8*j+7][d];
        bsplit(y0, hs, ls); hb.x = hs; lb.x = ls;
        bsplit(y1, hs, ls); hb.y = hs; lb.y = ls;
        bsplit(y2, hs, ls); hb.z = hs; lb.z = ls;
        bsplit(y3, hs, ls); hb.w = hs; lb.w = ls;
    }
    const size_t ob = (((size_t)b*NH + hh)*32 + d)*S_ + (size_t)(kb*2 + (j >> 2))*32;
    *(ushort4*)&vthi[ob + pa] = ha;
    *(ushort4*)&vthi[ob + pb] = hb;
    *(ushort4*)&vtlo[ob + pa] = la;
    *(ushort4*)&vtlo[ob + pb] = lb;
}

// ---------------- Flash attention: full-MFMA (R16-validated: 103.5us) -------------
// LDS-staged (global_load_lds), single vmcnt(0) drain + lgkm fence, stage(t+1)
// issued after K-frag reads. Softmax in BASE-2 (log2e folded into q scale):
// every exp is a bare v_exp_f32.
template<int NSPLIT>
__global__ __launch_bounds__(64) void attn_mfma(
        const unsigned short* __restrict__ qhi, const unsigned short* __restrict__ qlo,
        const unsigned short* __restrict__ khi, const unsigned short* __restrict__ klo,
        const unsigned short* __restrict__ vthi, const unsigned short* __restrict__ vtlo,
        float* __restrict__ outp, float* __restrict__ pm, float* __restrict__ pl)
{
    __shared__ unsigned short KH[1024];        // [kvh][16kv][32d], single-buffered
    __shared__ unsigned short KL[1024];
    __shared__ unsigned short VTH[2][1024];    // [buf][32 d][32 pi-slots]
    __shared__ unsigned short VTL[2][1024];

    const int tid = threadIdx.x;
    const int cq  = tid & 15;
    const int gq  = tid >> 4;                  // 0..3
    const int qb  = blockIdx.x * 32;
    const int hh  = blockIdx.y;
    const int split = blockIdx.z % NSPLIT;
    const int b     = blockIdx.z / NSPLIT;
    const int kt0   = split * (S_ / NSPLIT);
    const int NT    = (S_ / NSPLIT) / 32;      // 48 (split-2)

    const size_t rowbase = (size_t)b * S_;
    const int coloff = hh * HD;

    const int sd = tid >> 2;                   // 0..15
    const int sp = tid & 3;
    const int ss = sp ^ ((sd >> 1) & 3);

    const unsigned short* kh0 = khi + ((rowbase + kt0 + sd)*NH + hh)*32 + ss*8;
    const unsigned short* kl0 = klo + ((rowbase + kt0 + sd)*NH + hh)*32 + ss*8;
    const size_t vrow_a = (((size_t)b*NH + hh)*32 + sd)      * S_ + kt0;
    const size_t vrow_b = (((size_t)b*NH + hh)*32 + sd + 16) * S_ + kt0;
    const unsigned short* vh_a = vthi + vrow_a + ss*8;
    const unsigned short* vh_b = vthi + vrow_b + ss*8;
    const unsigned short* vl_a = vtlo + vrow_a + ss*8;
    const unsigned short* vl_b = vtlo + vrow_b + ss*8;

#define ISSUE_TILE(t_, vb_) { \
        const size_t ko = (size_t)(t_)*(32*NH*32); \
        const size_t vo = (size_t)(t_)*32; \
        gload_lds16(kh0 + ko,            &KH[0]);   \
        gload_lds16(kh0 + ko + 16*NH*32, &KH[512]); \
        gload_lds16(kl0 + ko,            &KL[0]);   \
        gload_lds16(kl0 + ko + 16*NH*32, &KL[512]); \
        gload_lds16(vh_a + vo, &VTH[vb_][0]);   \
        gload_lds16(vh_b + vo, &VTH[vb_][512]); \
        gload_lds16(vl_a + vo, &VTL[vb_][0]);   \
        gload_lds16(vl_b + vo, &VTL[vb_][512]); }

    ISSUE_TILE(0, 0);

    const size_t q0off = ((rowbase + qb +      cq)*NH + hh)*32 + gq*8;
    const size_t q1off = ((rowbase + qb + 16 + cq)*NH + hh)*32 + gq*8;
    const bf16x8 q0h = *(const bf16x8*)(qhi + q0off);
    const bf16x8 q0l = *(const bf16x8*)(qlo + q0off);
    const bf16x8 q1h = *(const bf16x8*)(qhi + q1off);
    const bf16x8 q1l = *(const bf16x8*)(qlo + q1off);

    const int slot = gq ^ ((cq >> 1) & 3);
    const int fo   = cq*32 + slot*8;

    float m = -1e30f;
    float l0 = 0.f, l1 = 0.f;
    f32x4 acc00 = {0,0,0,0}, acc01 = {0,0,0,0};   // [qh][dh]
    f32x4 acc10 = {0,0,0,0}, acc11 = {0,0,0,0};

    for (int t = 0; t < NT; ++t) {
        const int cur = t & 1;
        asm volatile("s_waitcnt vmcnt(0)" ::: "memory");   // stage(t) landed
        __builtin_amdgcn_sched_barrier(0);

        const bf16x8 kh0f = *(const bf16x8*)&KH[fo];
        const bf16x8 kh1f = *(const bf16x8*)&KH[512 + fo];
        const bf16x8 kl0f = *(const bf16x8*)&KL[fo];
        const bf16x8 kl1f = *(const bf16x8*)&KL[512 + fo];
        asm volatile("s_waitcnt lgkmcnt(0)" ::: "memory"); // frags retired
        __builtin_amdgcn_sched_barrier(0);
        if (t + 1 < NT) ISSUE_TILE(t + 1, cur ^ 1);

        __builtin_amdgcn_s_setprio(1);
        f32x4 s00 = {0,0,0,0}, s01 = {0,0,0,0}, s10 = {0,0,0,0}, s11 = {0,0,0,0};
        s00 = __builtin_amdgcn_mfma_f32_16x16x32_bf16(kh0f, q0h, s00, 0, 0, 0);
        s01 = __builtin_amdgcn_mfma_f32_16x16x32_bf16(kh1f, q0h, s01, 0, 0, 0);
        s10 = __builtin_amdgcn_mfma_f32_16x16x32_bf16(kh0f, q1h, s10, 0, 0, 0);
        s11 = __builtin_amdgcn_mfma_f32_16x16x32_bf16(kh1f, q1h, s11, 0, 0, 0);
        s00 = __builtin_amdgcn_mfma_f32_16x16x32_bf16(kh0f, q0l, s00, 0, 0, 0);
        s01 = __builtin_amdgcn_mfma_f32_16x16x32_bf16(kh1f, q0l, s01, 0, 0, 0);
        s10 = __builtin_amdgcn_mfma_f32_16x16x32_bf16(kh0f, q1l, s10, 0, 0, 0);
        s11 = __builtin_amdgcn_mfma_f32_16x16x32_bf16(kh1f, q1l, s11, 0, 0, 0);
        s00 = __builtin_amdgcn_mfma_f32_16x16x32_bf16(kl0f, q0h, s00, 0, 0, 0);
        s01 = __builtin_amdgcn_mfma_f32_16x16x32_bf16(kl1f, q0h, s01, 0, 0, 0);
        s10 = __builtin_amdgcn_mfma_f32_16x16x32_bf16(kl0f, q1h, s10, 0, 0, 0);
        s11 = __builtin_amdgcn_mfma_f32_16x16x32_bf16(kl1f, q1h, s11, 0, 0, 0);

        float lmax;
        {
            float a = fmaxf(fmaxf(s00[0], s00[1]), fmaxf(s00[2], s00[3]));
            float b2 = fmaxf(fmaxf(s01[0], s01[1]), fmaxf(s01[2], s01[3]));
            float c2 = fmaxf(fmaxf(s10[0], s10[1]), fmaxf(s10[2], s10[3]));
            float d2 = fmaxf(fmaxf(s11[0], s11[1]), fmaxf(s11[2], s11[3]));
            lmax = fmaxf(fmaxf(a, b2), fmaxf(c2, d2));
        }
        if (!__all(lmax - m <= 8.f)) {         // base-2 domain: p bounded by 2^8
            float wm = lmax;
            wm = fmaxf(wm, __shfl_xor(wm, 1));  wm = fmaxf(wm, __shfl_xor(wm, 2));
            wm = fmaxf(wm, __shfl_xor(wm, 4));  wm = fmaxf(wm, __shfl_xor(wm, 8));
            wm = fmaxf(wm, __shfl_xor(wm, 16)); wm = fmaxf(wm, __shfl_xor(wm, 32));
            const float mn = fmaxf(m, wm);
            const float f = fexp2(m - mn);
            m = mn; l0 *= f; l1 *= f;
            #pragma unroll
            for (int e = 0; e < 4; ++e) {
                acc00[e] *= f; acc01[e] *= f; acc10[e] *= f; acc11[e] *= f;
            }
        }
        float p00[4], p01[4], p10[4], p11[4];
        #pragma unroll
        for (int e = 0; e < 4; ++e) {
            p00[e] = fexp2(s00[e] - m);
            p01[e] = fexp2(s01[e] - m);
            p10[e] = fexp2(s10[e] - m);
            p11[e] = fexp2(s11[e] - m);
        }
        l0 += ((p00[0]+p00[1]) + (p00[2]+p00[3])) + ((p01[0]+p01[1]) + (p01[2]+p01[3]));
        l1 += ((p10[0]+p10[1]) + (p10[2]+p10[3])) + ((p11[0]+p11[1]) + (p11[2]+p11[3]));

        bf16x8 pah0, pal0, pah1, pal1;
        #pragma unroll
        for (int e = 0; e < 4; ++e) {
            __bf16 h;
            h = (__bf16)p00[e]; pah0[e]   = h; pal0[e]   = (__bf16)(p00[e] - (float)h);
            h = (__bf16)p01[e]; pah0[e+4] = h; pal0[e+4] = (__bf16)(p01[e] - (float)h);
            h = (__bf16)p10[e]; pah1[e]   = h; pal1[e]   = (__bf16)(p10[e] - (float)h);
            h = (__bf16)p11[e]; pah1[e+4] = h; pal1[e+4] = (__bf16)(p11[e] - (float)h);
        }

        const bf16x8 vh0 = *(const bf16x8*)&VTH[cur][fo];        // d = cq
        const bf16x8 vh1 = *(const bf16x8*)&VTH[cur][512 + fo];  // d = cq+16
        const bf16x8 vl0 = *(const bf16x8*)&VTL[cur][fo];
        const bf16x8 vl1 = *(const bf16x8*)&VTL[cur][512 + fo];

        acc00 = __builtin_amdgcn_mfma_f32_16x16x32_bf16(pah0, vh0, acc00, 0, 0, 0);
        acc01 = __builtin_amdgcn_mfma_f32_16x16x32_bf16(pah0, vh1, acc01, 0, 0, 0);
        acc10 = __builtin_amdgcn_mfma_f32_16x16x32_bf16(pah1, vh0, acc10, 0, 0, 0);
        acc11 = __builtin_amdgcn_mfma_f32_16x16x32_bf16(pah1, vh1, acc11, 0, 0, 0);
        acc00 = __builtin_amdgcn_mfma_f32_16x16x32_bf16(pah0, vl0, acc00, 0, 0, 0);
        acc01 = __builtin_amdgcn_mfma_f32_16x16x32_bf16(pah0, vl1, acc01, 0, 0, 0);
        acc10 = __builtin_amdgcn_mfma_f32_16x16x32_bf16(pah1, vl0, acc10, 0, 0, 0);
        acc11 = __builtin_amdgcn_mfma_f32_16x16x32_bf16(pah1, vl1, acc11, 0, 0, 0);
        acc00 = __builtin_amdgcn_mfma_f32_16x16x32_bf16(pal0, vh0, acc00, 0, 0, 0);
        acc01 = __builtin_amdgcn_mfma_f32_16x16x32_bf16(pal0, vh1, acc01, 0, 0, 0);
        acc10 = __builtin_amdgcn_mfma_f32_16x16x32_bf16(pal1, vh0, acc10, 0, 0, 0);
        acc11 = __builtin_amdgcn_mfma_f32_16x16x32_bf16(pal1, vh1, acc11, 0, 0, 0);
        __builtin_amdgcn_s_setprio(0);
    }
#undef ISSUE_TILE

    l0 += __shfl_xor(l0, 16); l0 += __shfl_xor(l0, 32);
    l1 += __shfl_xor(l1, 16); l1 += __shfl_xor(l1, 32);

    float lq0[4], lq1[4];
    #pragma unroll
    for (int r = 0; r < 4; ++r) {
        lq0[r] = __shfl(l0, 4*gq + r);
        lq1[r] = __shfl(l1, 4*gq + r);
    }

    float* obase = (NSPLIT == 1) ? outp : (outp + (size_t)split * NELEM);
    #pragma unroll
    for (int r = 0; r < 4; ++r) {
        const int qrow = qb + 4*gq + r;
        const float i0 = (NSPLIT == 1) ? 1.f / lq0[r] : 1.f;
        const float i1 = (NSPLIT == 1) ? 1.f / lq1[r] : 1.f;
        obase[(rowbase + qrow)*C_ + coloff + cq]           = acc00[r]*i0;
        obase[(rowbase + qrow)*C_ + coloff + 16 + cq]      = acc01[r]*i0;
        obase[(rowbase + qrow + 16)*C_ + coloff + cq]      = acc10[r]*i1;
        obase[(rowbase + qrow + 16)*C_ + coloff + 16 + cq] = acc11[r]*i1;
    }

    if (NSPLIT > 1 && gq == 0) {
        const size_t mlb = (size_t)split*MLROWS + ((size_t)b*NH + hh)*S_;
        pm[mlb + qb + cq]      = m;  pl[mlb + qb + cq]      = l0;  // m in log2 domain
        pm[mlb + qb + 16 + cq] = m;  pl[mlb + qb + 16 + cq] = l1;
    }
}

// ---------------- fp32 fallback attention (R12, validated) ------------------------
__global__ __launch_bounds__(64) void attn_fp32(
        const float* __restrict__ q, const float* __restrict__ k,
        const float* __restrict__ v, float* __restrict__ outp)
{
    __shared__ float SM[2][2][16*32];

    const int tid  = threadIdx.x;
    const int sub  = tid & 3;
    const int g    = tid >> 2;
    const int qb   = blockIdx.x * 32;
    const int hh   = blockIdx.y;
    const int b    = blockIdx.z;
    const int NT   = S_ / 16;

    const size_t rowbase = (size_t)b * S_;
    const int coloff = hh * HD;

    const int srow  = tid >> 3;
    const int sxcol = (((tid & 7) ^ (srow & 3)) << 2);
    const float* kstage = &k[(rowbase + srow)*C_ + coloff + sxcol];
    const float* vstage = &v[(rowbase + srow)*C_ + coloff + sxcol];

    const int r0 = qb + g, r1 = qb + g + 16;

#define ISSUE_TILE(t_, bufi) { \
        const float* gk = kstage + (size_t)(t_)*(16*C_); \
        const float* gv = vstage + (size_t)(t_)*(16*C_); \
        float* lk = &SM[bufi][0][0]; \
        float* lv = &SM[bufi][1][0]; \
        gload_lds16(gk        , lk      ); \
        gload_lds16(gk +  8*C_, lk + 256); \
        gload_lds16(gv        , lv      ); \
        gload_lds16(gv +  8*C_, lv + 256); }

    ISSUE_TILE(0, 0);

    float q0[32], q1[32];
    #pragma unroll
    for (int k4 = 0; k4 < 32; k4 += 4) {
        float4 t0 = *(const float4*)&q[(rowbase + r0)*C_ + coloff + k4];
        float4 t1 = *(const float4*)&q[(rowbase + r1)*C_ + coloff + k4];
        q0[k4+0]=t0.x; q0[k4+1]=t0.y; q0[k4+2]=t0.z; q0[k4+3]=t0.w;
        q1[k4+0]=t1.x; q1[k4+1]=t1.y; q1[k4+2]=t1.z; q1[k4+3]=t1.w;
    }

    float m0 = -1e30f, m1 = -1e30f, l0 = 0.f, l1 = 0.f;
    float a0[32] = {}, a1[32] = {};

    for (int t = 0; t < NT; ++t) {
        const int cur = t & 1;
        if (t + 1 < NT) {
            ISSUE_TILE(t + 1, cur ^ 1);
            asm volatile("s_waitcnt vmcnt(4)" ::: "memory");
        } else {
            asm volatile("s_waitcnt vmcnt(0)" ::: "memory");
        }
        __builtin_amdgcn_sched_barrier(0);

        const float* Kc = &SM[cur][0][0];
        const float* Vc = &SM[cur][1][0];

        float s0_[4], s1_[4];
        #pragma unroll
        for (int i = 0; i < 4; ++i) {
            const float* kr = Kc + (sub + 4*i)*32;
            float d0 = 0.f, d1 = 0.f;
            #pragma unroll
            for (int c4 = 0; c4 < 8; ++c4) {
                float4 kk = *(const float4*)&kr[(c4 ^ sub) << 2];
                d0 += q0[c4*4+0]*kk.x + q0[c4*4+1]*kk.y + q0[c4*4+2]*kk.z + q0[c4*4+3]*kk.w;
                d1 += q1[c4*4+0]*kk.x + q1[c4*4+1]*kk.y + q1[c4*4+2]*kk.z + q1[c4*4+3]*kk.w;
            }
            s0_[i] = d0; s1_[i] = d1;
        }
        {
            float tm0 = fmaxf(fmaxf(s0_[0], s0_[1]), fmaxf(s0_[2], s0_[3]));
            float tm1 = fmaxf(fmaxf(s1_[0], s1_[1]), fmaxf(s1_[2], s1_[3]));
            tm0 = fmaxf(tm0, __shfl_xor(tm0, 1)); tm0 = fmaxf(tm0, __shfl_xor(tm0, 2));
            tm1 = fmaxf(tm1, __shfl_xor(tm1, 1)); tm1 = fmaxf(tm1, __shfl_xor(tm1, 2));
            if (!__all((tm0 - m0 <= 8.f) && (tm1 - m1 <= 8.f))) {
                const float mn0 = fmaxf(m0, tm0), mn1 = fmaxf(m1, tm1);
                const float f0 = __expf(m0 - mn0), f1 = __expf(m1 - mn1);
                m0 = mn0; m1 = mn1; l0 *= f0; l1 *= f1;
                #pragma unroll
                for (int d = 0; d < 32; ++d) { a0[d] *= f0; a1[d] *= f1; }
            }
            #pragma unroll
            for (int i = 0; i < 4; ++i) {
                s0_[i] = __expf(s0_[i] - m0);
                s1_[i] = __expf(s1_[i] - m1);
            }
            l0 += (s0_[0] + s0_[1]) + (s0_[2] + s0_[3]);
            l1 += (s1_[0] + s1_[1]) + (s1_[2] + s1_[3]);
        }
        #pragma unroll
        for (int i = 0; i < 4; ++i) {
            const float* vr = Vc + (sub + 4*i)*32;
            const float pj0 = s0_[i], pj1 = s1_[i];
            #pragma unroll
            for (int d4 = 0; d4 < 8; ++d4) {
                float4 vv = *(const float4*)&vr[(d4 ^ sub) << 2];
                a0[d4*4+0] += pj0*vv.x; a0[d4*4+1] += pj0*vv.y;
                a0[d4*4+2] += pj0*vv.z; a0[d4*4+3] += pj0*vv.w;
                a1[d4*4+0] += pj1*vv.x; a1[d4*4+1] += pj1*vv.y;
                a1[d4*4+2] += pj1*vv.z; a1[d4*4+3] += pj1*vv.w;
            }
        }
    }
#undef ISSUE_TILE

    l0 += __shfl_xor(l0, 1); l0 += __shfl_xor(l0, 2);
    l1 += __shfl_xor(l1, 1); l1 += __shfl_xor(l1, 2);
    const float inv0 = 1.f / l0, inv1 = 1.f / l1;
    #pragma unroll
    for (int d = 0; d < 32; ++d) {
        float x0 = a0[d]; x0 += __shfl_xor(x0, 1); x0 += __shfl_xor(x0, 2); a0[d] = x0 * inv0;
        float x1 = a1[d]; x1 += __shfl_xor(x1, 1); x1 += __shfl_xor(x1, 2); a1[d] = x1 * inv1;
    }
    #define WRITE_SLICE(ro, a_, off) { \
        float4 o1 = make_float4(a_[(off)+0],a_[(off)+1],a_[(off)+2],a_[(off)+3]); \
        float4 o2 = make_float4(a_[(off)+4],a_[(off)+5],a_[(off)+6],a_[(off)+7]); \
        *(float4*)&outp[(rowbase + (ro))*C_ + coloff + (off)]     = o1; \
        *(float4*)&outp[(rowbase + (ro))*C_ + coloff + (off) + 4] = o2; }
    if      (sub == 0) { WRITE_SLICE(r0, a0, 0)  WRITE_SLICE(r1, a1, 0)  }
    else if (sub == 1) { WRITE_SLICE(r0, a0, 8)  WRITE_SLICE(r1, a1, 8)  }
    else if (sub == 2) { WRITE_SLICE(r0, a0, 16) WRITE_SLICE(r1, a1, 16) }
    else               { WRITE_SLICE(r0, a0, 24) WRITE_SLICE(r1, a1, 24) }
    #undef WRITE_SLICE
}

// ---------------- combine the NSPLIT partials -> ctx bf16 splits ------------------
// NOTE: pm is in LOG2 domain (matches attn_mfma's base-2 softmax)
template<int NSPLIT>
__global__ __launch_bounds__(256) void combine_split_kernel(
        const float* __restrict__ pacc, const float* __restrict__ pm,
        const float* __restrict__ pl,
        unsigned short* __restrict__ chi, unsigned short* __restrict__ clo)
{
    const int gid = blockIdx.x * 256 + threadIdx.x;
    int rem = gid >> 3;
    const int h = rem & 7; rem >>= 3;
    const int s = rem % S_;
    const int b = rem / S_;

    const size_t i0 = ((size_t)b*NH + h)*S_ + s;
    float mm[NSPLIT], ll[NSPLIT], w[NSPLIT];
    float M = -1e30f;
    #pragma unroll
    for (int i = 0; i < NSPLIT; ++i) {
        mm[i] = pm[i0 + (size_t)i*MLROWS];
        ll[i] = pl[i0 + (size_t)i*MLROWS];
        M = fmaxf(M, mm[i]);
    }
    float L = 0.f;
    #pragma unroll
    for (int i = 0; i < NSPLIT; ++i) { w[i] = fexp2(mm[i] - M); L += ll[i]*w[i]; }
    const float invL = 1.f / L;

    const size_t a = (size_t)gid * 4;
    float4 o = make_float4(0.f, 0.f, 0.f, 0.f);
    #pragma unroll
    for (int i = 0; i < NSPLIT; ++i) {
        const float4 x = *(const float4*)&pacc[a + (size_t)i*NELEM];
        o.x += x.x*w[i]; o.y += x.y*w[i]; o.z += x.z*w[i]; o.w += x.w*w[i];
    }
    o.x *= invL; o.y *= invL; o.z *= invL; o.w *= invL;
    ushort4 hv, lv; unsigned short hh, ll2;
    bsplit(o.x, hh, ll2); hv.x = hh; lv.x = ll2;
    bsplit(o.y, hh, ll2); hv.y = hh; lv.y = ll2;
    bsplit(o.z, hh, ll2); hv.z = hh; lv.z = ll2;
    bsplit(o.w, hh, ll2); hv.w = hh; lv.w = ll2;
    *(ushort4*)&chi[a] = hv;
    *(ushort4*)&clo[a] = lv;
}

// ---------------- launch ---------------------------------------------------------
extern "C" void kernel_launch(void* const* d_in, const int* in_sizes, int n_in,
                              void* d_out, int out_size, void* d_ws, size_t ws_size,
                              hipStream_t stream)
{
    const float* x  = (const float*)d_in[0];
    const float* Wq = (const float*)d_in[1];
    const float* Wk = (const float*)d_in[2];
    const float* Wv = (const float*)d_in[3];
    const float* qb = (const float*)d_in[4];
    const float* vb = (const float*)d_in[5];
    const float* Wo = (const float*)d_in[6];
    const float* bo = (const float*)d_in[7];
    float* out = (float*)d_out;

    float* ws   = (float*)d_ws;
    float* q    = ws;
    float* k    = q + NELEM;
    float* v    = k + NELEM;
    float* ctx  = v + NELEM;                         // fallback fp32 ctx; mfma: Wo splits
    float* tblf = ctx + NELEM;                       // rope table: TABN float2
    float* pacc = tblf + 2*TABN;                     // 2 x NELEM (mfma: x+W splits early)
    float* pm   = pacc + (size_t)2*NELEM;            // 2 x MLROWS
    float* pl   = pm + (size_t)2*MLROWS;             // 2 x MLROWS
    unsigned short* qhi  = (unsigned short*)(pl + (size_t)2*MLROWS);
    unsigned short* qlo  = qhi + (size_t)NELEM;
    unsigned short* khi  = qlo + (size_t)NELEM;
    unsigned short* klo  = khi + (size_t)NELEM;
    unsigned short* vthi = klo + (size_t)NELEM;
    unsigned short* vtlo = vthi + (size_t)NELEM;

    // ---- aliases (mfma path; all into regions dead at time of use) ----
    unsigned short* xhi = (unsigned short*)pacc;     // dead before attn writes pacc
    unsigned short* xlo = xhi + (size_t)NELEM;
    unsigned short* wqh = xlo + (size_t)NELEM;       // 6*65536 ushorts, still in pacc
    unsigned short* wql = wqh + 65536;
    unsigned short* wkh = wql + 65536;
    unsigned short* wkl = wkh + 65536;
    unsigned short* wvh = wkl + 65536;
    unsigned short* wvl = wvh + 65536;
    unsigned short* woh = (unsigned short*)ctx;      // ctx unused on mfma path
    unsigned short* wol = woh + 65536;
    unsigned short* chi = qhi;                       // q splits dead after attn
    unsigned short* clo = qlo;

    const size_t need = ((size_t)9*NELEM + 2*TABN + 4*MLROWS) * sizeof(float);

    if (ws_size >= need) {
        float2* tbl = (float2*)tblf;
        // 1) fused prep: x split + weight splits + rope table (one launch)
        prep_kernel<<<1984, 256, 0, stream>>>(x, Wq, Wk, Wv, Wo,
                xhi, xlo, wqh, wql, wkh, wkl, wvh, wvl, woh, wol, tbl);
        // 2) q,k,v projections on the matrix pipe (q pre-scaled incl. log2e)
        qkv_mfma_kernel<<<dim3((B_*S_)/32, C_/32, 3), 64, 0, stream>>>(
                xhi, xlo, wqh, wql, wkh, wkl, wvh, wvl, qb, vb, q, k, v);
        // 3) rope (+ q/k bf16 split emission)
        rope_kernel<true><<<6144, 256, 0, stream>>>(q, k, tbl, qhi, qlo, khi, klo);
        // 4) V transpose + split, pi-ordered
        vsplit_kernel<<<dim3(S_/64, NH, B_), 256, 0, stream>>>(v, vthi, vtlo);
        // 5) full-MFMA attention (R16-validated schedule, base-2 softmax)
        attn_mfma<2><<<dim3(S_/32, NH, B_*2), 64, 0, stream>>>(
            qhi, qlo, khi, klo, vthi, vtlo, pacc, pm, pl);
        // 6) combine partials -> ctx bf16 splits (into dead q-split region)
        combine_split_kernel<2><<<(B_*S_*NH*8)/256, 256, 0, stream>>>(
            pacc, pm, pl, chi, clo);
        // 7) output projection on the matrix pipe
        out_gemm_mfma_kernel<<<dim3((B_*S_)/32, C_/32), 64, 0, stream>>>(
            chi, clo, woh, wol, bo, out);
    } else {
        // full fp32 fallback chain (R16-validated, natural-e softmax)
        qkv_kernel<<<dim3(96, 4, 3), 256, 0, stream>>>(x, Wq, Wk, Wv, qb, vb, q, k, v);
        rope_kernel<false><<<6144, 256, 0, stream>>>(q, k, nullptr,
                                                     nullptr, nullptr, nullptr, nullptr);
        attn_fp32<<<dim3(S_/32, NH, B_), 64, 0, stream>>>(q, k, v, ctx);
        out_gemm_kernel<<<dim3(96, 4, 1), 256, 0, stream>>>(ctx, Wo, bo, out);
    }
}

// Round 22
// 168.492 us; speedup vs baseline: 1.0636x; 1.0636x over previous
//
#include <hip/hip_runtime.h>
#include <math.h>

#define B_   2
#define S_   3072
#define C_   256
#define NH   8
#define HD   32
#define HALF 16
#define NELEM (B_*S_*C_)   // 1,572,864
#define MLROWS (B_*NH*S_)  // 49,152 rows per split
#define TABN  (S_*HALF)    // 49,152 rope table entries

typedef __attribute__((ext_vector_type(8))) __bf16 bf16x8;
typedef __attribute__((ext_vector_type(4))) float  f32x4;

__device__ __forceinline__ float dot4(float4 a, float4 b) {
    return a.x*b.x + a.y*b.y + a.z*b.z + a.w*b.w;
}

// direct global->LDS copy, 16B per lane; LDS dest is wave-uniform base + lane*16
__device__ __forceinline__ void gload_lds16(const void* g, void* l) {
    __builtin_amdgcn_global_load_lds(
        (const __attribute__((address_space(1))) unsigned int*)g,
        (__attribute__((address_space(3))) unsigned int*)l, 16, 0, 0);
}

// fp32 -> (hi, lo) bf16 split: hi = bf16(x), lo = bf16(x - hi). hi*hi+hi*lo+lo*hi
// reconstructs products to ~2^-17 relative.
__device__ __forceinline__ void bsplit(float x, unsigned short& h, unsigned short& lo) {
    __bf16 hb = (__bf16)x;
    float hf = (float)hb;
    __bf16 lb = (__bf16)(x - hf);
    h  = __builtin_bit_cast(unsigned short, hb);
    lo = __builtin_bit_cast(unsigned short, lb);
}

// ---------------- fused prep: x split | W splits | rope table ----------------------
// grid 1984 blocks: [0,1536) fsplit(x), [1536,1792) wsplit, [1792,1984) rope table
__global__ __launch_bounds__(256) void prep_kernel(
        const float* __restrict__ x,
        const float* __restrict__ Wq, const float* __restrict__ Wk,
        const float* __restrict__ Wv, const float* __restrict__ Wo,
        unsigned short* __restrict__ xhi, unsigned short* __restrict__ xlo,
        unsigned short* __restrict__ wqh, unsigned short* __restrict__ wql,
        unsigned short* __restrict__ wkh, unsigned short* __restrict__ wkl,
        unsigned short* __restrict__ wvh, unsigned short* __restrict__ wvl,
        unsigned short* __restrict__ woh, unsigned short* __restrict__ wol,
        float2* __restrict__ tbl)
{
    const int bx = blockIdx.x;
    const int tid = threadIdx.x;
    if (bx < 1536) {                       // x split: NELEM/4 float4s
        const size_t i = (size_t)bx * 256 + tid;
        float4 xv = *(const float4*)&x[i*4];
        ushort4 h, l; unsigned short hh, ll;
        bsplit(xv.x, hh, ll); h.x = hh; l.x = ll;
        bsplit(xv.y, hh, ll); h.y = hh; l.y = ll;
        bsplit(xv.z, hh, ll); h.z = hh; l.z = ll;
        bsplit(xv.w, hh, ll); h.w = hh; l.w = ll;
        *(ushort4*)&xhi[i*4] = h;
        *(ushort4*)&xlo[i*4] = l;
    } else if (bx < 1792) {                // weight splits: 4 mats x 64 blocks
        const int wb  = bx - 1536;
        const int mat = wb >> 6;
        const float* src; unsigned short *h, *l;
        if      (mat == 0) { src = Wq; h = wqh; l = wql; }
        else if (mat == 1) { src = Wk; h = wkh; l = wkl; }
        else if (mat == 2) { src = Wv; h = wvh; l = wvl; }
        else               { src = Wo; h = woh; l = wol; }
        const size_t i = (size_t)(wb & 63) * 256 + tid;
        float4 xv = *(const float4*)&src[i*4];
        ushort4 hv, lv; unsigned short hh, ll;
        bsplit(xv.x, hh, ll); hv.x = hh; lv.x = ll;
        bsplit(xv.y, hh, ll); hv.y = hh; lv.y = ll;
        bsplit(xv.z, hh, ll); hv.z = hh; lv.z = ll;
        bsplit(xv.w, hh, ll); hv.w = hh; lv.w = ll;
        *(ushort4*)&h[i*4] = hv;
        *(ushort4*)&l[i*4] = lv;
    } else {                               // rope table: 192 blocks
        const int idx = (bx - 1792) * 256 + tid;   // 0..49151
        const int j = idx & 15;
        const int s = idx >> 4;
        const double invf = exp(-log(10000.0) * (double)j * (1.0 / 16.0));
        const float  angf = (float)((double)s * invf);
        double sn, cs;
        sincos((double)angf, &sn, &cs);
        tbl[idx] = make_float2((float)cs, (float)sn);
    }
}

// ---------------- MFMA GEMM: out[M x 256] = (A @ W^T (+bias)) * scl ---------------
// 1 wave per 32x32 output tile; operands as bf16 hi/lo [row][256]; 3-term split.
// Frags loaded DIRECTLY from global (L2-resident; 64B segments per 4-lane group).
// D-layout (R14/R15-verified): row(n) = 16nh + 4gq + reg, col(m) = 16mh + cq.
__device__ __forceinline__ void gemm_mfma_body(
        const unsigned short* __restrict__ Ahi, const unsigned short* __restrict__ Alo,
        const unsigned short* __restrict__ Whi, const unsigned short* __restrict__ Wlo,
        const float* __restrict__ bias, float* __restrict__ out, float scl)
{
    const int tid = threadIdx.x;
    const int cq  = tid & 15;
    const int gq  = tid >> 4;
    const int m0  = blockIdx.x * 32;
    const int n0  = blockIdx.y * 32;

    const size_t a0 = (size_t)(m0 + cq)      * C_ + gq*8;   // B-op rows (m)
    const size_t a1 = (size_t)(m0 + 16 + cq) * C_ + gq*8;
    const size_t w0 = (size_t)(n0 + cq)      * C_ + gq*8;   // A-op rows (n)
    const size_t w1 = (size_t)(n0 + 16 + cq) * C_ + gq*8;

    f32x4 acc00 = {0,0,0,0}, acc01 = {0,0,0,0};   // [nh][mh]
    f32x4 acc10 = {0,0,0,0}, acc11 = {0,0,0,0};

    #pragma unroll
    for (int kk = 0; kk < 8; ++kk) {
        const int ko = kk * 32;
        const bf16x8 wh0 = *(const bf16x8*)(Whi + w0 + ko);
        const bf16x8 wh1 = *(const bf16x8*)(Whi + w1 + ko);
        const bf16x8 wl0 = *(const bf16x8*)(Wlo + w0 + ko);
        const bf16x8 wl1 = *(const bf16x8*)(Wlo + w1 + ko);
        const bf16x8 ah0 = *(const bf16x8*)(Ahi + a0 + ko);
        const bf16x8 ah1 = *(const bf16x8*)(Ahi + a1 + ko);
        const bf16x8 al0 = *(const bf16x8*)(Alo + a0 + ko);
        const bf16x8 al1 = *(const bf16x8*)(Alo + a1 + ko);
        acc00 = __builtin_amdgcn_mfma_f32_16x16x32_bf16(wh0, ah0, acc00, 0, 0, 0);
        acc01 = __builtin_amdgcn_mfma_f32_16x16x32_bf16(wh0, ah1, acc01, 0, 0, 0);
        acc10 = __builtin_amdgcn_mfma_f32_16x16x32_bf16(wh1, ah0, acc10, 0, 0, 0);
        acc11 = __builtin_amdgcn_mfma_f32_16x16x32_bf16(wh1, ah1, acc11, 0, 0, 0);
        acc00 = __builtin_amdgcn_mfma_f32_16x16x32_bf16(wh0, al0, acc00, 0, 0, 0);
        acc01 = __builtin_amdgcn_mfma_f32_16x16x32_bf16(wh0, al1, acc01, 0, 0, 0);
        acc10 = __builtin_amdgcn_mfma_f32_16x16x32_bf16(wh1, al0, acc10, 0, 0, 0);
        acc11 = __builtin_amdgcn_mfma_f32_16x16x32_bf16(wh1, al1, acc11, 0, 0, 0);
        acc00 = __builtin_amdgcn_mfma_f32_16x16x32_bf16(wl0, ah0, acc00, 0, 0, 0);
        acc01 = __builtin_amdgcn_mfma_f32_16x16x32_bf16(wl0, ah1, acc01, 0, 0, 0);
        acc10 = __builtin_amdgcn_mfma_f32_16x16x32_bf16(wl1, ah0, acc10, 0, 0, 0);
        acc11 = __builtin_amdgcn_mfma_f32_16x16x32_bf16(wl1, ah1, acc11, 0, 0, 0);
    }

    float4 bv0 = make_float4(0.f, 0.f, 0.f, 0.f);
    float4 bv1 = make_float4(0.f, 0.f, 0.f, 0.f);
    if (bias) {
        bv0 = *(const float4*)&bias[n0 + 4*gq];
        bv1 = *(const float4*)&bias[n0 + 16 + 4*gq];
    }
    float4 o;
    o = make_float4((acc00[0]+bv0.x)*scl, (acc00[1]+bv0.y)*scl,
                    (acc00[2]+bv0.z)*scl, (acc00[3]+bv0.w)*scl);
    *(float4*)&out[(size_t)(m0 + cq)*C_ + n0 + 4*gq] = o;
    o = make_float4((acc01[0]+bv0.x)*scl, (acc01[1]+bv0.y)*scl,
                    (acc01[2]+bv0.z)*scl, (acc01[3]+bv0.w)*scl);
    *(float4*)&out[(size_t)(m0 + 16 + cq)*C_ + n0 + 4*gq] = o;
    o = make_float4((acc10[0]+bv1.x)*scl, (acc10[1]+bv1.y)*scl,
                    (acc10[2]+bv1.z)*scl, (acc10[3]+bv1.w)*scl);
    *(float4*)&out[(size_t)(m0 + cq)*C_ + n0 + 16 + 4*gq] = o;
    o = make_float4((acc11[0]+bv1.x)*scl, (acc11[1]+bv1.y)*scl,
                    (acc11[2]+bv1.z)*scl, (acc11[3]+bv1.w)*scl);
    *(float4*)&out[(size_t)(m0 + 16 + cq)*C_ + n0 + 16 + 4*gq] = o;
}

__global__ __launch_bounds__(64) void qkv_mfma_kernel(
        const unsigned short* __restrict__ xhi, const unsigned short* __restrict__ xlo,
        const unsigned short* __restrict__ wqh, const unsigned short* __restrict__ wql,
        const unsigned short* __restrict__ wkh, const unsigned short* __restrict__ wkl,
        const unsigned short* __restrict__ wvh, const unsigned short* __restrict__ wvl,
        const float* __restrict__ qb, const float* __restrict__ vb,
        float* __restrict__ q, float* __restrict__ k, float* __restrict__ v)
{
    if (blockIdx.z == 0)
        gemm_mfma_body(xhi, xlo, wqh, wql, qb, q, 0.17677669529663687f);
    else if (blockIdx.z == 1)
        gemm_mfma_body(xhi, xlo, wkh, wkl, nullptr, k, 1.0f);
    else
        gemm_mfma_body(xhi, xlo, wvh, wvl, vb, v, 1.0f);
}

__global__ __launch_bounds__(64) void out_gemm_mfma_kernel(
        const unsigned short* __restrict__ chi, const unsigned short* __restrict__ clo,
        const unsigned short* __restrict__ woh, const unsigned short* __restrict__ wol,
        const float* __restrict__ bo, float* __restrict__ out)
{
    gemm_mfma_body(chi, clo, woh, wol, bo, out, 1.0f);
}

// ---------------- fp32 GEMM (fallback path only; R16-validated) -------------------
__device__ __forceinline__ void gemm_nt_body(const float* __restrict__ A,
                                             const float* __restrict__ W,
                                             const float* __restrict__ bias,
                                             float* __restrict__ out,
                                             float scl)
{
    __shared__ float As[2][64*32];
    __shared__ float Ws[2][64*32];

    const int tid  = threadIdx.x;
    const int wv   = tid >> 6;
    const int tx4  = (tid & 15) * 4;
    const int ty4  = (tid >> 4) * 4;
    const int row0 = blockIdx.x * 64;
    const int col0 = blockIdx.y * 64;

    const int d0  = tid, d1 = tid + 256;
    const int r0s = d0 >> 3, r1s = d1 >> 3;
    const int c0s = (d0 & 7) ^ ((r0s >> 2) & 7);
    const int c1s = (d1 & 7) ^ ((r1s >> 2) & 7);
    const float* a0p = A + (size_t)(row0 + r0s)*C_ + c0s*4;
    const float* a1p = A + (size_t)(row0 + r1s)*C_ + c1s*4;
    const float* w0p = W + (size_t)(col0 + r0s)*C_ + c0s*4;
    const float* w1p = W + (size_t)(col0 + r1s)*C_ + c1s*4;
    const int dst = wv * 256;

#define GSTAGE(kc, buf) { \
        gload_lds16(a0p + (kc), &As[buf][dst]);        \
        gload_lds16(a1p + (kc), &As[buf][dst + 1024]); \
        gload_lds16(w0p + (kc), &Ws[buf][dst]);        \
        gload_lds16(w1p + (kc), &Ws[buf][dst + 1024]); }

    float acc[4][4] = {};
    const int xa = ((tid >> 4) & 7) * 4;
    const int xw = (tid & 7) * 4;

    GSTAGE(0, 0);
    __syncthreads();

    for (int kk = 0; kk < 8; ++kk) {
        const int buf = kk & 1;
        if (kk + 1 < 8) GSTAGE((kk + 1) * 32, buf ^ 1);

        const float* Ab = &As[buf][ty4 * 32];
        const float* Wb = &Ws[buf][tx4 * 32];
        #pragma unroll
        for (int p = 0; p < 8; ++p) {
            const int oa = (p * 4) ^ xa;
            const int ow = (p * 4) ^ xw;
            float4 a0 = *(const float4*)&Ab[oa];
            float4 a1 = *(const float4*)&Ab[32 + oa];
            float4 a2 = *(const float4*)&Ab[64 + oa];
            float4 a3 = *(const float4*)&Ab[96 + oa];
            float4 w0 = *(const float4*)&Wb[ow];
            float4 w1 = *(const float4*)&Wb[32 + ow];
            float4 w2 = *(const float4*)&Wb[64 + ow];
            float4 w3 = *(const float4*)&Wb[96 + ow];
            acc[0][0] += dot4(a0,w0); acc[0][1] += dot4(a0,w1);
            acc[0][2] += dot4(a0,w2); acc[0][3] += dot4(a0,w3);
            acc[1][0] += dot4(a1,w0); acc[1][1] += dot4(a1,w1);
            acc[1][2] += dot4(a1,w2); acc[1][3] += dot4(a1,w3);
            acc[2][0] += dot4(a2,w0); acc[2][1] += dot4(a2,w1);
            acc[2][2] += dot4(a2,w2); acc[2][3] += dot4(a2,w3);
            acc[3][0] += dot4(a3,w0); acc[3][1] += dot4(a3,w1);
            acc[3][2] += dot4(a3,w2); acc[3][3] += dot4(a3,w3);
        }
        __syncthreads();
    }
#undef GSTAGE

    float4 bv = make_float4(0.f, 0.f, 0.f, 0.f);
    if (bias) bv = *(const float4*)&bias[col0 + tx4];
    #pragma unroll
    for (int rr = 0; rr < 4; ++rr) {
        float4 o = make_float4((acc[rr][0] + bv.x)*scl, (acc[rr][1] + bv.y)*scl,
                               (acc[rr][2] + bv.z)*scl, (acc[rr][3] + bv.w)*scl);
        *(float4*)&out[(size_t)(row0 + ty4 + rr)*C_ + col0 + tx4] = o;
    }
}

__global__ __launch_bounds__(256) void qkv_kernel(
        const float* __restrict__ x,
        const float* __restrict__ Wq, const float* __restrict__ Wk, const float* __restrict__ Wv,
        const float* __restrict__ qb, const float* __restrict__ vb,
        float* __restrict__ q, float* __restrict__ k, float* __restrict__ v)
{
    if      (blockIdx.z == 0) gemm_nt_body(x, Wq, qb,      q, 0.17677669529663687f);
    else if (blockIdx.z == 1) gemm_nt_body(x, Wk, nullptr, k, 1.0f);
    else                      gemm_nt_body(x, Wv, vb,      v, 1.0f);
}

__global__ __launch_bounds__(256) void out_gemm_kernel(
        const float* __restrict__ ctx, const float* __restrict__ Wo,
        const float* __restrict__ bo, float* __restrict__ out)
{
    gemm_nt_body(ctx, Wo, bo, out, 1.0f);
}

// ---------------- RoPE (in place on q and k); TAB path also emits bf16 splits -----
template<bool TAB>
__global__ __launch_bounds__(256) void rope_kernel(float* __restrict__ q, float* __restrict__ k,
                                                   const float2* __restrict__ tbl,
                                                   unsigned short* __restrict__ qhi,
                                                   unsigned short* __restrict__ qlo,
                                                   unsigned short* __restrict__ khi,
                                                   unsigned short* __restrict__ klo)
{
    const int idx = blockIdx.x * 256 + threadIdx.x;
    const int per_tensor = B_ * S_ * NH * HALF;       // 786432
    const bool isq = (idx < per_tensor);
    float* t = isq ? q : k;
    const int i   = isq ? idx : idx - per_tensor;
    const int j   = i & 15;
    const int hh  = (i >> 4) & 7;
    const int row = i >> 7;
    const int s   = (row >= S_) ? (row - S_) : row;

    float c, sf;
    if (TAB) {
        const float2 cs2 = tbl[(s << 4) | j];
        c = cs2.x; sf = cs2.y;
    } else {
        const double invf = exp(-log(10000.0) * (double)j * (1.0 / 16.0));
        const float  angf = (float)((double)s * invf);
        double sn, cd;
        sincos((double)angf, &sn, &cd);
        c = (float)cd; sf = (float)sn;
    }

    const size_t base = (size_t)row * C_ + hh * HD + j;
    const float t1 = t[base];
    const float t2 = t[base + HALF];
    const float o1 = t1 * c - t2 * sf;
    const float o2 = t2 * c + t1 * sf;
    t[base]        = o1;
    t[base + HALF] = o2;

    if (TAB) {
        unsigned short* hi = isq ? qhi : khi;
        unsigned short* lo = isq ? qlo : klo;
        const size_t sb = ((size_t)row * NH + hh) * 32;
        unsigned short h1, l1, h2, l2;
        bsplit(o1, h1, l1);
        bsplit(o2, h2, l2);
        hi[sb + j]      = h1;  lo[sb + j]      = l1;
        hi[sb + j + 16] = h2;  lo[sb + j + 16] = l2;
    }
}

// ---------------- V transpose + bf16 split, pi-ordered -----------------------------
__global__ __launch_bounds__(256) void vsplit_kernel(const float* __restrict__ v,
                                                     unsigned short* __restrict__ vthi,
                                                     unsigned short* __restrict__ vtlo)
{
    __shared__ float T[64][33];
    const int t  = threadIdx.x;
    const int kb = blockIdx.x;       // 64-kv chunk (0..47)
    const int hh = blockIdx.y;
    const int b  = blockIdx.z;
    const size_t rowbase = (size_t)b*S_ + kb*64;

    {   // load 64 rows x 32 d, coalesced
        const int r = t >> 2;        // 0..63
        const int p = t & 3;         // float4 piece
        float4 a  = *(const float4*)&v[(rowbase + r)*C_ + hh*32 + p*4];
        float4 b2 = *(const float4*)&v[(rowbase + r)*C_ + hh*32 + 16 + p*4];
        *(float4*)&T[r][p*4]      = a;
        *(float4*)&T[r][16 + p*4] = b2;
    }
    __syncthreads();

    const int d = t >> 3;
    const int j = t & 7;
    const int pa = (j & 1)*16 + ((j & 2) ? 4 : 0);   // pi position of first 4-run
    const int pb = pa + 8;                           // second 4-run
    ushort4 ha, la, hb, lb;
    unsigned short hs, ls;
    {
        float x0 = T[8*j+0][d], x1 = T[8*j+1][d], x2 = T[8*j+2][d], x3 = T[8*j+3][d];
        bsplit(x0, hs, ls); ha.x = hs; la.x = ls;
        bsplit(x1, hs, ls); ha.y = hs; la.y = ls;
        bsplit(x2, hs, ls); ha.z = hs; la.z = ls;
        bsplit(x3, hs, ls); ha.w = hs; la.w = ls;
        float y0 = T[8*j+4][d], y1 = T[8*j+5][d], y2 = T[8*j+6][d], y3 = T[8*j+7][d];
        bsplit(y0, hs, ls); hb.x = hs; lb.x = ls;
        bsplit(y1, hs, ls); hb.y = hs; lb.y = ls;
        bsplit(y2, hs, ls); hb.z = hs; lb.z = ls;
        bsplit(y3, hs, ls); hb.w = hs; lb.w = ls;
    }
    const size_t ob = (((size_t)b*NH + hh)*32 + d)*S_ + (size_t)(kb*2 + (j >> 2))*32;
    *(ushort4*)&vthi[ob + pa] = ha;
    *(ushort4*)&vthi[ob + pb] = hb;
    *(ushort4*)&vtlo[ob + pa] = la;
    *(ushort4*)&vtlo[ob + pb] = lb;
}

// ---------------- Flash attention: full-MFMA (R16-validated: 103.5us) -------------
// LDS-staged (global_load_lds), single vmcnt(0) drain + lgkm fence, stage(t+1)
// issued after K-frag reads. R17 (split counted waits), R18 (LDS-free register
// prefetch), and R21 (base-2 softmax via inline-asm exp) all regressed: this
// schedule is a verified local optimum; the LDS bounce IS the prefetch buffer.
template<int NSPLIT>
__global__ __launch_bounds__(64) void attn_mfma(
        const unsigned short* __restrict__ qhi, const unsigned short* __restrict__ qlo,
        const unsigned short* __restrict__ khi, const unsigned short* __restrict__ klo,
        const unsigned short* __restrict__ vthi, const unsigned short* __restrict__ vtlo,
        float* __restrict__ outp, float* __restrict__ pm, float* __restrict__ pl)
{
    __shared__ unsigned short KH[1024];        // [kvh][16kv][32d], single-buffered
    __shared__ unsigned short KL[1024];
    __shared__ unsigned short VTH[2][1024];    // [buf][32 d][32 pi-slots]
    __shared__ unsigned short VTL[2][1024];

    const int tid = threadIdx.x;
    const int cq  = tid & 15;
    const int gq  = tid >> 4;                  // 0..3
    const int qb  = blockIdx.x * 32;
    const int hh  = blockIdx.y;
    const int split = blockIdx.z % NSPLIT;
    const int b     = blockIdx.z / NSPLIT;
    const int kt0   = split * (S_ / NSPLIT);
    const int NT    = (S_ / NSPLIT) / 32;      // 48 (split-2)

    const size_t rowbase = (size_t)b * S_;
    const int coloff = hh * HD;

    const int sd = tid >> 2;                   // 0..15
    const int sp = tid & 3;
    const int ss = sp ^ ((sd >> 1) & 3);

    const unsigned short* kh0 = khi + ((rowbase + kt0 + sd)*NH + hh)*32 + ss*8;
    const unsigned short* kl0 = klo + ((rowbase + kt0 + sd)*NH + hh)*32 + ss*8;
    const size_t vrow_a = (((size_t)b*NH + hh)*32 + sd)      * S_ + kt0;
    const size_t vrow_b = (((size_t)b*NH + hh)*32 + sd + 16) * S_ + kt0;
    const unsigned short* vh_a = vthi + vrow_a + ss*8;
    const unsigned short* vh_b = vthi + vrow_b + ss*8;
    const unsigned short* vl_a = vtlo + vrow_a + ss*8;
    const unsigned short* vl_b = vtlo + vrow_b + ss*8;

#define ISSUE_TILE(t_, vb_) { \
        const size_t ko = (size_t)(t_)*(32*NH*32); \
        const size_t vo = (size_t)(t_)*32; \
        gload_lds16(kh0 + ko,            &KH[0]);   \
        gload_lds16(kh0 + ko + 16*NH*32, &KH[512]); \
        gload_lds16(kl0 + ko,            &KL[0]);   \
        gload_lds16(kl0 + ko + 16*NH*32, &KL[512]); \
        gload_lds16(vh_a + vo, &VTH[vb_][0]);   \
        gload_lds16(vh_b + vo, &VTH[vb_][512]); \
        gload_lds16(vl_a + vo, &VTL[vb_][0]);   \
        gload_lds16(vl_b + vo, &VTL[vb_][512]); }

    ISSUE_TILE(0, 0);

    const size_t q0off = ((rowbase + qb +      cq)*NH + hh)*32 + gq*8;
    const size_t q1off = ((rowbase + qb + 16 + cq)*NH + hh)*32 + gq*8;
    const bf16x8 q0h = *(const bf16x8*)(qhi + q0off);
    const bf16x8 q0l = *(const bf16x8*)(qlo + q0off);
    const bf16x8 q1h = *(const bf16x8*)(qhi + q1off);
    const bf16x8 q1l = *(const bf16x8*)(qlo + q1off);

    const int slot = gq ^ ((cq >> 1) & 3);
    const int fo   = cq*32 + slot*8;

    float m = -1e30f;
    float l0 = 0.f, l1 = 0.f;
    f32x4 acc00 = {0,0,0,0}, acc01 = {0,0,0,0};   // [qh][dh]
    f32x4 acc10 = {0,0,0,0}, acc11 = {0,0,0,0};

    for (int t = 0; t < NT; ++t) {
        const int cur = t & 1;
        asm volatile("s_waitcnt vmcnt(0)" ::: "memory");   // stage(t) landed
        __builtin_amdgcn_sched_barrier(0);

        const bf16x8 kh0f = *(const bf16x8*)&KH[fo];
        const bf16x8 kh1f = *(const bf16x8*)&KH[512 + fo];
        const bf16x8 kl0f = *(const bf16x8*)&KL[fo];
        const bf16x8 kl1f = *(const bf16x8*)&KL[512 + fo];
        asm volatile("s_waitcnt lgkmcnt(0)" ::: "memory"); // frags retired
        __builtin_amdgcn_sched_barrier(0);
        if (t + 1 < NT) ISSUE_TILE(t + 1, cur ^ 1);

        __builtin_amdgcn_s_setprio(1);
        f32x4 s00 = {0,0,0,0}, s01 = {0,0,0,0}, s10 = {0,0,0,0}, s11 = {0,0,0,0};
        s00 = __builtin_amdgcn_mfma_f32_16x16x32_bf16(kh0f, q0h, s00, 0, 0, 0);
        s01 = __builtin_amdgcn_mfma_f32_16x16x32_bf16(kh1f, q0h, s01, 0, 0, 0);
        s10 = __builtin_amdgcn_mfma_f32_16x16x32_bf16(kh0f, q1h, s10, 0, 0, 0);
        s11 = __builtin_amdgcn_mfma_f32_16x16x32_bf16(kh1f, q1h, s11, 0, 0, 0);
        s00 = __builtin_amdgcn_mfma_f32_16x16x32_bf16(kh0f, q0l, s00, 0, 0, 0);
        s01 = __builtin_amdgcn_mfma_f32_16x16x32_bf16(kh1f, q0l, s01, 0, 0, 0);
        s10 = __builtin_amdgcn_mfma_f32_16x16x32_bf16(kh0f, q1l, s10, 0, 0, 0);
        s11 = __builtin_amdgcn_mfma_f32_16x16x32_bf16(kh1f, q1l, s11, 0, 0, 0);
        s00 = __builtin_amdgcn_mfma_f32_16x16x32_bf16(kl0f, q0h, s00, 0, 0, 0);
        s01 = __builtin_amdgcn_mfma_f32_16x16x32_bf16(kl1f, q0h, s01, 0, 0, 0);
        s10 = __builtin_amdgcn_mfma_f32_16x16x32_bf16(kl0f, q1h, s10, 0, 0, 0);
        s11 = __builtin_amdgcn_mfma_f32_16x16x32_bf16(kl1f, q1h, s11, 0, 0, 0);

        float lmax;
        {
            float a = fmaxf(fmaxf(s00[0], s00[1]), fmaxf(s00[2], s00[3]));
            float b2 = fmaxf(fmaxf(s01[0], s01[1]), fmaxf(s01[2], s01[3]));
            float c2 = fmaxf(fmaxf(s10[0], s10[1]), fmaxf(s10[2], s10[3]));
            float d2 = fmaxf(fmaxf(s11[0], s11[1]), fmaxf(s11[2], s11[3]));
            lmax = fmaxf(fmaxf(a, b2), fmaxf(c2, d2));
        }
        if (!__all(lmax - m <= 8.f)) {
            float wm = lmax;
            wm = fmaxf(wm, __shfl_xor(wm, 1));  wm = fmaxf(wm, __shfl_xor(wm, 2));
            wm = fmaxf(wm, __shfl_xor(wm, 4));  wm = fmaxf(wm, __shfl_xor(wm, 8));
            wm = fmaxf(wm, __shfl_xor(wm, 16)); wm = fmaxf(wm, __shfl_xor(wm, 32));
            const float mn = fmaxf(m, wm);
            const float f = __expf(m - mn);
            m = mn; l0 *= f; l1 *= f;
            #pragma unroll
            for (int e = 0; e < 4; ++e) {
                acc00[e] *= f; acc01[e] *= f; acc10[e] *= f; acc11[e] *= f;
            }
        }
        float p00[4], p01[4], p10[4], p11[4];
        #pragma unroll
        for (int e = 0; e < 4; ++e) {
            p00[e] = __expf(s00[e] - m);
            p01[e] = __expf(s01[e] - m);
            p10[e] = __expf(s10[e] - m);
            p11[e] = __expf(s11[e] - m);
        }
        l0 += ((p00[0]+p00[1]) + (p00[2]+p00[3])) + ((p01[0]+p01[1]) + (p01[2]+p01[3]));
        l1 += ((p10[0]+p10[1]) + (p10[2]+p10[3])) + ((p11[0]+p11[1]) + (p11[2]+p11[3]));

        bf16x8 pah0, pal0, pah1, pal1;
        #pragma unroll
        for (int e = 0; e < 4; ++e) {
            __bf16 h;
            h = (__bf16)p00[e]; pah0[e]   = h; pal0[e]   = (__bf16)(p00[e] - (float)h);
            h = (__bf16)p01[e]; pah0[e+4] = h; pal0[e+4] = (__bf16)(p01[e] - (float)h);
            h = (__bf16)p10[e]; pah1[e]   = h; pal1[e]   = (__bf16)(p10[e] - (float)h);
            h = (__bf16)p11[e]; pah1[e+4] = h; pal1[e+4] = (__bf16)(p11[e] - (float)h);
        }

        const bf16x8 vh0 = *(const bf16x8*)&VTH[cur][fo];        // d = cq
        const bf16x8 vh1 = *(const bf16x8*)&VTH[cur][512 + fo];  // d = cq+16
        const bf16x8 vl0 = *(const bf16x8*)&VTL[cur][fo];
        const bf16x8 vl1 = *(const bf16x8*)&VTL[cur][512 + fo];

        acc00 = __builtin_amdgcn_mfma_f32_16x16x32_bf16(pah0, vh0, acc00, 0, 0, 0);
        acc01 = __builtin_amdgcn_mfma_f32_16x16x32_bf16(pah0, vh1, acc01, 0, 0, 0);
        acc10 = __builtin_amdgcn_mfma_f32_16x16x32_bf16(pah1, vh0, acc10, 0, 0, 0);
        acc11 = __builtin_amdgcn_mfma_f32_16x16x32_bf16(pah1, vh1, acc11, 0, 0, 0);
        acc00 = __builtin_amdgcn_mfma_f32_16x16x32_bf16(pah0, vl0, acc00, 0, 0, 0);
        acc01 = __builtin_amdgcn_mfma_f32_16x16x32_bf16(pah0, vl1, acc01, 0, 0, 0);
        acc10 = __builtin_amdgcn_mfma_f32_16x16x32_bf16(pah1, vl0, acc10, 0, 0, 0);
        acc11 = __builtin_amdgcn_mfma_f32_16x16x32_bf16(pah1, vl1, acc11, 0, 0, 0);
        acc00 = __builtin_amdgcn_mfma_f32_16x16x32_bf16(pal0, vh0, acc00, 0, 0, 0);
        acc01 = __builtin_amdgcn_mfma_f32_16x16x32_bf16(pal0, vh1, acc01, 0, 0, 0);
        acc10 = __builtin_amdgcn_mfma_f32_16x16x32_bf16(pal1, vh0, acc10, 0, 0, 0);
        acc11 = __builtin_amdgcn_mfma_f32_16x16x32_bf16(pal1, vh1, acc11, 0, 0, 0);
        __builtin_amdgcn_s_setprio(0);
    }
#undef ISSUE_TILE

    l0 += __shfl_xor(l0, 16); l0 += __shfl_xor(l0, 32);
    l1 += __shfl_xor(l1, 16); l1 += __shfl_xor(l1, 32);

    float lq0[4], lq1[4];
    #pragma unroll
    for (int r = 0; r < 4; ++r) {
        lq0[r] = __shfl(l0, 4*gq + r);
        lq1[r] = __shfl(l1, 4*gq + r);
    }

    float* obase = (NSPLIT == 1) ? outp : (outp + (size_t)split * NELEM);
    #pragma unroll
    for (int r = 0; r < 4; ++r) {
        const int qrow = qb + 4*gq + r;
        const float i0 = (NSPLIT == 1) ? 1.f / lq0[r] : 1.f;
        const float i1 = (NSPLIT == 1) ? 1.f / lq1[r] : 1.f;
        obase[(rowbase + qrow)*C_ + coloff + cq]           = acc00[r]*i0;
        obase[(rowbase + qrow)*C_ + coloff + 16 + cq]      = acc01[r]*i0;
        obase[(rowbase + qrow + 16)*C_ + coloff + cq]      = acc10[r]*i1;
        obase[(rowbase + qrow + 16)*C_ + coloff + 16 + cq] = acc11[r]*i1;
    }

    if (NSPLIT > 1 && gq == 0) {
        const size_t mlb = (size_t)split*MLROWS + ((size_t)b*NH + hh)*S_;
        pm[mlb + qb + cq]      = m;  pl[mlb + qb + cq]      = l0;
        pm[mlb + qb + 16 + cq] = m;  pl[mlb + qb + 16 + cq] = l1;
    }
}

// ---------------- fp32 fallback attention (R12, validated) ------------------------
__global__ __launch_bounds__(64) void attn_fp32(
        const float* __restrict__ q, const float* __restrict__ k,
        const float* __restrict__ v, float* __restrict__ outp)
{
    __shared__ float SM[2][2][16*32];

    const int tid  = threadIdx.x;
    const int sub  = tid & 3;
    const int g    = tid >> 2;
    const int qb   = blockIdx.x * 32;
    const int hh   = blockIdx.y;
    const int b    = blockIdx.z;
    const int NT   = S_ / 16;

    const size_t rowbase = (size_t)b * S_;
    const int coloff = hh * HD;

    const int srow  = tid >> 3;
    const int sxcol = (((tid & 7) ^ (srow & 3)) << 2);
    const float* kstage = &k[(rowbase + srow)*C_ + coloff + sxcol];
    const float* vstage = &v[(rowbase + srow)*C_ + coloff + sxcol];

    const int r0 = qb + g, r1 = qb + g + 16;

#define ISSUE_TILE(t_, bufi) { \
        const float* gk = kstage + (size_t)(t_)*(16*C_); \
        const float* gv = vstage + (size_t)(t_)*(16*C_); \
        float* lk = &SM[bufi][0][0]; \
        float* lv = &SM[bufi][1][0]; \
        gload_lds16(gk        , lk      ); \
        gload_lds16(gk +  8*C_, lk + 256); \
        gload_lds16(gv        , lv      ); \
        gload_lds16(gv +  8*C_, lv + 256); }

    ISSUE_TILE(0, 0);

    float q0[32], q1[32];
    #pragma unroll
    for (int k4 = 0; k4 < 32; k4 += 4) {
        float4 t0 = *(const float4*)&q[(rowbase + r0)*C_ + coloff + k4];
        float4 t1 = *(const float4*)&q[(rowbase + r1)*C_ + coloff + k4];
        q0[k4+0]=t0.x; q0[k4+1]=t0.y; q0[k4+2]=t0.z; q0[k4+3]=t0.w;
        q1[k4+0]=t1.x; q1[k4+1]=t1.y; q1[k4+2]=t1.z; q1[k4+3]=t1.w;
    }

    float m0 = -1e30f, m1 = -1e30f, l0 = 0.f, l1 = 0.f;
    float a0[32] = {}, a1[32] = {};

    for (int t = 0; t < NT; ++t) {
        const int cur = t & 1;
        if (t + 1 < NT) {
            ISSUE_TILE(t + 1, cur ^ 1);
            asm volatile("s_waitcnt vmcnt(4)" ::: "memory");
        } else {
            asm volatile("s_waitcnt vmcnt(0)" ::: "memory");
        }
        __builtin_amdgcn_sched_barrier(0);

        const float* Kc = &SM[cur][0][0];
        const float* Vc = &SM[cur][1][0];

        float s0_[4], s1_[4];
        #pragma unroll
        for (int i = 0; i < 4; ++i) {
            const float* kr = Kc + (sub + 4*i)*32;
            float d0 = 0.f, d1 = 0.f;
            #pragma unroll
            for (int c4 = 0; c4 < 8; ++c4) {
                float4 kk = *(const float4*)&kr[(c4 ^ sub) << 2];
                d0 += q0[c4*4+0]*kk.x + q0[c4*4+1]*kk.y + q0[c4*4+2]*kk.z + q0[c4*4+3]*kk.w;
                d1 += q1[c4*4+0]*kk.x + q1[c4*4+1]*kk.y + q1[c4*4+2]*kk.z + q1[c4*4+3]*kk.w;
            }
            s0_[i] = d0; s1_[i] = d1;
        }
        {
            float tm0 = fmaxf(fmaxf(s0_[0], s0_[1]), fmaxf(s0_[2], s0_[3]));
            float tm1 = fmaxf(fmaxf(s1_[0], s1_[1]), fmaxf(s1_[2], s1_[3]));
            tm0 = fmaxf(tm0, __shfl_xor(tm0, 1)); tm0 = fmaxf(tm0, __shfl_xor(tm0, 2));
            tm1 = fmaxf(tm1, __shfl_xor(tm1, 1)); tm1 = fmaxf(tm1, __shfl_xor(tm1, 2));
            if (!__all((tm0 - m0 <= 8.f) && (tm1 - m1 <= 8.f))) {
                const float mn0 = fmaxf(m0, tm0), mn1 = fmaxf(m1, tm1);
                const float f0 = __expf(m0 - mn0), f1 = __expf(m1 - mn1);
                m0 = mn0; m1 = mn1; l0 *= f0; l1 *= f1;
                #pragma unroll
                for (int d = 0; d < 32; ++d) { a0[d] *= f0; a1[d] *= f1; }
            }
            #pragma unroll
            for (int i = 0; i < 4; ++i) {
                s0_[i] = __expf(s0_[i] - m0);
                s1_[i] = __expf(s1_[i] - m1);
            }
            l0 += (s0_[0] + s0_[1]) + (s0_[2] + s0_[3]);
            l1 += (s1_[0] + s1_[1]) + (s1_[2] + s1_[3]);
        }
        #pragma unroll
        for (int i = 0; i < 4; ++i) {
            const float* vr = Vc + (sub + 4*i)*32;
            const float pj0 = s0_[i], pj1 = s1_[i];
            #pragma unroll
            for (int d4 = 0; d4 < 8; ++d4) {
                float4 vv = *(const float4*)&vr[(d4 ^ sub) << 2];
                a0[d4*4+0] += pj0*vv.x; a0[d4*4+1] += pj0*vv.y;
                a0[d4*4+2] += pj0*vv.z; a0[d4*4+3] += pj0*vv.w;
                a1[d4*4+0] += pj1*vv.x; a1[d4*4+1] += pj1*vv.y;
                a1[d4*4+2] += pj1*vv.z; a1[d4*4+3] += pj1*vv.w;
            }
        }
    }
#undef ISSUE_TILE

    l0 += __shfl_xor(l0, 1); l0 += __shfl_xor(l0, 2);
    l1 += __shfl_xor(l1, 1); l1 += __shfl_xor(l1, 2);
    const float inv0 = 1.f / l0, inv1 = 1.f / l1;
    #pragma unroll
    for (int d = 0; d < 32; ++d) {
        float x0 = a0[d]; x0 += __shfl_xor(x0, 1); x0 += __shfl_xor(x0, 2); a0[d] = x0 * inv0;
        float x1 = a1[d]; x1 += __shfl_xor(x1, 1); x1 += __shfl_xor(x1, 2); a1[d] = x1 * inv1;
    }
    #define WRITE_SLICE(ro, a_, off) { \
        float4 o1 = make_float4(a_[(off)+0],a_[(off)+1],a_[(off)+2],a_[(off)+3]); \
        float4 o2 = make_float4(a_[(off)+4],a_[(off)+5],a_[(off)+6],a_[(off)+7]); \
        *(float4*)&outp[(rowbase + (ro))*C_ + coloff + (off)]     = o1; \
        *(float4*)&outp[(rowbase + (ro))*C_ + coloff + (off) + 4] = o2; }
    if      (sub == 0) { WRITE_SLICE(r0, a0, 0)  WRITE_SLICE(r1, a1, 0)  }
    else if (sub == 1) { WRITE_SLICE(r0, a0, 8)  WRITE_SLICE(r1, a1, 8)  }
    else if (sub == 2) { WRITE_SLICE(r0, a0, 16) WRITE_SLICE(r1, a1, 16) }
    else               { WRITE_SLICE(r0, a0, 24) WRITE_SLICE(r1, a1, 24) }
    #undef WRITE_SLICE
}

// ---------------- combine the NSPLIT partials -> ctx bf16 splits ------------------
template<int NSPLIT>
__global__ __launch_bounds__(256) void combine_split_kernel(
        const float* __restrict__ pacc, const float* __restrict__ pm,
        const float* __restrict__ pl,
        unsigned short* __restrict__ chi, unsigned short* __restrict__ clo)
{
    const int gid = blockIdx.x * 256 + threadIdx.x;
    int rem = gid >> 3;
    const int h = rem & 7; rem >>= 3;
    const int s = rem % S_;
    const int b = rem / S_;

    const size_t i0 = ((size_t)b*NH + h)*S_ + s;
    float mm[NSPLIT], ll[NSPLIT], w[NSPLIT];
    float M = -1e30f;
    #pragma unroll
    for (int i = 0; i < NSPLIT; ++i) {
        mm[i] = pm[i0 + (size_t)i*MLROWS];
        ll[i] = pl[i0 + (size_t)i*MLROWS];
        M = fmaxf(M, mm[i]);
    }
    float L = 0.f;
    #pragma unroll
    for (int i = 0; i < NSPLIT; ++i) { w[i] = __expf(mm[i] - M); L += ll[i]*w[i]; }
    const float invL = 1.f / L;

    const size_t a = (size_t)gid * 4;
    float4 o = make_float4(0.f, 0.f, 0.f, 0.f);
    #pragma unroll
    for (int i = 0; i < NSPLIT; ++i) {
        const float4 x = *(const float4*)&pacc[a + (size_t)i*NELEM];
        o.x += x.x*w[i]; o.y += x.y*w[i]; o.z += x.z*w[i]; o.w += x.w*w[i];
    }
    o.x *= invL; o.y *= invL; o.z *= invL; o.w *= invL;
    ushort4 hv, lv; unsigned short hh, ll2;
    bsplit(o.x, hh, ll2); hv.x = hh; lv.x = ll2;
    bsplit(o.y, hh, ll2); hv.y = hh; lv.y = ll2;
    bsplit(o.z, hh, ll2); hv.z = hh; lv.z = ll2;
    bsplit(o.w, hh, ll2); hv.w = hh; lv.w = ll2;
    *(ushort4*)&chi[a] = hv;
    *(ushort4*)&clo[a] = lv;
}

// ---------------- launch ---------------------------------------------------------
extern "C" void kernel_launch(void* const* d_in, const int* in_sizes, int n_in,
                              void* d_out, int out_size, void* d_ws, size_t ws_size,
                              hipStream_t stream)
{
    const float* x  = (const float*)d_in[0];
    const float* Wq = (const float*)d_in[1];
    const float* Wk = (const float*)d_in[2];
    const float* Wv = (const float*)d_in[3];
    const float* qb = (const float*)d_in[4];
    const float* vb = (const float*)d_in[5];
    const float* Wo = (const float*)d_in[6];
    const float* bo = (const float*)d_in[7];
    float* out = (float*)d_out;

    float* ws   = (float*)d_ws;
    float* q    = ws;
    float* k    = q + NELEM;
    float* v    = k + NELEM;
    float* ctx  = v + NELEM;                         // fallback fp32 ctx; mfma: Wo splits
    float* tblf = ctx + NELEM;                       // rope table: TABN float2
    float* pacc = tblf + 2*TABN;                     // 2 x NELEM (mfma: x+W splits early)
    float* pm   = pacc + (size_t)2*NELEM;            // 2 x MLROWS
    float* pl   = pm + (size_t)2*MLROWS;             // 2 x MLROWS
    unsigned short* qhi  = (unsigned short*)(pl + (size_t)2*MLROWS);
    unsigned short* qlo  = qhi + (size_t)NELEM;
    unsigned short* khi  = qlo + (size_t)NELEM;
    unsigned short* klo  = khi + (size_t)NELEM;
    unsigned short* vthi = klo + (size_t)NELEM;
    unsigned short* vtlo = vthi + (size_t)NELEM;

    // ---- aliases (mfma path; all into regions dead at time of use) ----
    unsigned short* xhi = (unsigned short*)pacc;     // dead before attn writes pacc
    unsigned short* xlo = xhi + (size_t)NELEM;
    unsigned short* wqh = xlo + (size_t)NELEM;       // 6*65536 ushorts, still in pacc
    unsigned short* wql = wqh + 65536;
    unsigned short* wkh = wql + 65536;
    unsigned short* wkl = wkh + 65536;
    unsigned short* wvh = wkl + 65536;
    unsigned short* wvl = wvh + 65536;
    unsigned short* woh = (unsigned short*)ctx;      // ctx unused on mfma path
    unsigned short* wol = woh + 65536;
    unsigned short* chi = qhi;                       // q splits dead after attn
    unsigned short* clo = qlo;

    const size_t need = ((size_t)9*NELEM + 2*TABN + 4*MLROWS) * sizeof(float);

    if (ws_size >= need) {
        float2* tbl = (float2*)tblf;
        // 1) fused prep: x split + weight splits + rope table (one launch)
        prep_kernel<<<1984, 256, 0, stream>>>(x, Wq, Wk, Wv, Wo,
                xhi, xlo, wqh, wql, wkh, wkl, wvh, wvl, woh, wol, tbl);
        // 2) q,k,v projections on the matrix pipe (q pre-scaled)
        qkv_mfma_kernel<<<dim3((B_*S_)/32, C_/32, 3), 64, 0, stream>>>(
                xhi, xlo, wqh, wql, wkh, wkl, wvh, wvl, qb, vb, q, k, v);
        // 3) rope (+ q/k bf16 split emission)
        rope_kernel<true><<<6144, 256, 0, stream>>>(q, k, tbl, qhi, qlo, khi, klo);
        // 4) V transpose + split, pi-ordered
        vsplit_kernel<<<dim3(S_/64, NH, B_), 256, 0, stream>>>(v, vthi, vtlo);
        // 5) full-MFMA attention (R16-validated schedule)
        attn_mfma<2><<<dim3(S_/32, NH, B_*2), 64, 0, stream>>>(
            qhi, qlo, khi, klo, vthi, vtlo, pacc, pm, pl);
        // 6) combine partials -> ctx bf16 splits (into dead q-split region)
        combine_split_kernel<2><<<(B_*S_*NH*8)/256, 256, 0, stream>>>(
            pacc, pm, pl, chi, clo);
        // 7) output projection on the matrix pipe
        out_gemm_mfma_kernel<<<dim3((B_*S_)/32, C_/32), 64, 0, stream>>>(
            chi, clo, woh, wol, bo, out);
    } else {
        // full fp32 fallback chain (R16-validated)
        qkv_kernel<<<dim3(96, 4, 3), 256, 0, stream>>>(x, Wq, Wk, Wv, qb, vb, q, k, v);
        rope_kernel<false><<<6144, 256, 0, stream>>>(q, k, nullptr,
                                                     nullptr, nullptr, nullptr, nullptr);
        attn_fp32<<<dim3(S_/32, NH, B_), 64, 0, stream>>>(q, k, v, ctx);
        out_gemm_kernel<<<dim3(96, 4, 1), 256, 0, stream>>>(ctx, Wo, bo, out);
    }
}